// Round 1
// 182.156 us; speedup vs baseline: 1.1714x; 1.1714x over previous
//
#include <hip/hip_runtime.h>
#include <hip/hip_fp16.h>

#define BLANKC 59

typedef _Float16 half8 __attribute__((ext_vector_type(8)));

// Wave-wide shift-right-by-1 via DPP: VALU-speed cross-lane. Lane 0 gets `fill`.
__device__ __forceinline__ float wave_shr1(float x, float fill) {
    int r = __builtin_amdgcn_update_dpp(__float_as_int(fill), __float_as_int(x),
                                        0x138 /* WAVE_SHR:1 */, 0xF, 0xF, false);
    return __int_as_float(r);
}

template <int CTRL>
__device__ __forceinline__ float dpp_fmax(float x) {
    int r = __builtin_amdgcn_update_dpp(__float_as_int(x), __float_as_int(x),
                                        CTRL, 0xF, 0xF, false);
    return fmaxf(x, __int_as_float(r));
}

// Full-wave max, broadcast to all lanes (6 DPP fmax + readlane).
__device__ __forceinline__ float wave_max_bcast(float x) {
    x = dpp_fmax<0x111>(x);   // row_shr:1
    x = dpp_fmax<0x112>(x);   // row_shr:2
    x = dpp_fmax<0x114>(x);   // row_shr:4
    x = dpp_fmax<0x118>(x);   // row_shr:8
    x = dpp_fmax<0x142>(x);   // row_bcast:15
    x = dpp_fmax<0x143>(x);   // row_bcast:31
    return __int_as_float(__builtin_amdgcn_readlane(__float_as_int(x), 63));
}

// ---------------- Phase 1: softmax + gather, TRANSPOSED output --------------
// em layout: [B][48 slots][T] halves, now storing PROBABILITIES exp(logp).
// slot l (0..44) = p[lab[b][l]], slot 45 = p[BLANK].
#define TTILE 64
__global__ __launch_bounds__(256)
void ctc_emit(const int* __restrict__ labels, const float* __restrict__ logits,
              __half* __restrict__ em, int T, int V, int L) {
    const int tiles_per_b = 384 / TTILE;                 // T = 384
    const int b  = blockIdx.x / tiles_per_b;
    const int t0 = (blockIdx.x % tiles_per_b) * TTILE;
    const int tid = threadIdx.x;

    __shared__ float ftile[TTILE][61];                   // stride 61: conflict-free
    __shared__ __half otile[48][72];                     // stride 72 halves (16B rows)

    const float* src = logits + ((long)b * T + t0) * V;  // 3840 contiguous floats
    #pragma unroll
    for (int it = 0; it < 15; ++it) {
        const int idx = it * 256 + tid;                  // 0..3839
        const int r = idx / 60, c = idx - r * 60;
        ftile[r][c] = src[idx];
    }
    __syncthreads();

    {   // LSE + gather: 4 lanes per t
        const int t = tid >> 2;
        const int q = tid & 3;
        float s = 0.f;
        #pragma unroll
        for (int k = 0; k < 15; ++k) s += __expf(ftile[t][q * 15 + k]);
        s += __shfl_xor(s, 1, 64);
        s += __shfl_xor(s, 2, 64);
        const float lse = __logf(s);
        const int* lab = labels + (long)b * L;
        #pragma unroll
        for (int j = 0; j < 12; ++j) {
            const int l = q * 12 + j;
            if (l < 46) {
                const int v = (l < 45) ? lab[l] : BLANKC;
                otile[l][t] = __float2half(__expf(ftile[t][v] - lse));  // probability
            }
        }
    }
    __syncthreads();

    for (int i = tid; i < 46 * 8; i += 256) {
        const int slot = i >> 3, seg = i & 7;
        const float4 v = *(const float4*)&otile[slot][seg * 8];
        float4* dst = (float4*)(em + ((long)b * 48 + slot) * T + t0 + seg * 8);
        *dst = v;
    }
}

// ---------------- Phase 2: alpha recurrence in LINEAR domain ----------------
// Lane l owns s0 = 2l (blank) and s1 = 2l+1 (label l). All alphas are linear
// probabilities with a wave-uniform power-of-2 scale; dead states are exact 0.
// Renormalize max -> 2^80 every 8 steps (exponent-field arithmetic only).
// No transcendentals anywhere in the T-loop.
#define RS 400   // LDS row stride in halves
__global__ __launch_bounds__(64)
void ctc_alpha(const int* __restrict__ labels, const __half* __restrict__ em,
               float* __restrict__ out, int T, int L, float inv_b) {
    const int b    = blockIdx.x;
    const int lane = threadIdx.x;

    __shared__ __half S[47 * RS];                        // 37.6 KB -> 4 blocks/CU

    // cooperative copy: em[b] slots 0..45 -> LDS rows; row 46 = zeros (phantom)
    const __half* emb = em + (long)b * 48 * T;
    const int NSEG = T / 8;                              // 48
    for (int i = lane; i < 46 * NSEG; i += 64) {
        const int r = i / NSEG, seg = i - r * NSEG;
        const half8 v = *(const half8*)(emb + r * T + seg * 8);
        *(half8*)(&S[r * RS + seg * 8]) = v;
    }
    for (int i = lane; i < T; i += 64) S[46 * RS + i] = __float2half(0.f);
    __syncthreads();

    const int* lab = labels + (long)b * L;
    const int labL = (lane < L) ? lab[lane] : BLANKC;
    const int labP = (lane >= 1 && lane < L) ? lab[lane - 1] : BLANKC;
    const float skipf = ((lane >= 1) && (lane < L) && (labL != BLANKC) && (labL != labP))
                        ? 1.0f : 0.0f;

    unsigned long long mk = __ballot((lane < L) && (labL != BLANKC));
    const int len = __popcll(mk);

    // Lane 45's s1 (state 91) and lanes >=46 are phantoms: feed them zeros so
    // they stay exactly 0 and never pollute the wave max.
    const __half* zrow = &S[46 * RS];
    const __half* rowL = (lane < 45) ? &S[lane * RS] : zrow;
    const __half* rowB = (lane < 46) ? &S[45 * RS] : zrow;

    half8 curL = *(const half8*)(rowL);
    half8 curB = *(const half8*)(rowB);

    // init at t=0, pre-scaled by 2^80 (anchor): only s=0,1 alive
    float a0 = (lane == 0) ? (float)curB[0] * 0x1p80f : 0.f;
    float a1 = (lane == 0) ? (float)curL[0] * 0x1p80f : 0.f;
    int esum = 80;                                       // stored = true * 2^esum

    auto step = [&](float eL, float eB) {
        const float p   = wave_shr1(a1, 0.0f);           // alpha_old[2l-1]
        const float t1  = a0 + a1;
        const float na0 = (a0 + p) * eB;
        const float na1 = fmaf(skipf, p, t1) * eL;
        a0 = na0; a1 = na1;
    };

    auto renorm = [&]() {
        const float m = wave_max_bcast(fmaxf(a0, a1));   // wave-uniform, > 0
        const int e = (__float_as_int(m) >> 23) & 0xff;
        int sexp = 207 - e;                              // scale max to ~2^80
        if (sexp > 127) sexp = 127;
        const float sc = __int_as_float((sexp + 127) << 23);   // 2^sexp
        a0 *= sc; a1 *= sc;
        esum += sexp;
    };

    // chunk 0: t = 1..7 (prefetch chunk 1 first)
    half8 nL = *(const half8*)(rowL + 8);
    half8 nB = *(const half8*)(rowB + 8);
    #pragma unroll
    for (int i = 1; i < 8; ++i) step((float)curL[i], (float)curB[i]);
    renorm();

    for (int c = 1; c < NSEG - 1; ++c) {
        const half8 cL = nL, cB = nB;
        nL = *(const half8*)(rowL + (c + 1) * 8);        // prefetch next chunk
        nB = *(const half8*)(rowB + (c + 1) * 8);
        #pragma unroll
        for (int i = 0; i < 8; ++i) step((float)cL[i], (float)cB[i]);
        renorm();
    }
    #pragma unroll
    for (int i = 0; i < 8; ++i) step((float)nL[i], (float)nB[i]);

    // epilogue: end = 2*len -> lane len's a0; end-1 -> lane (len-1)'s a1
    const float ab2 = __shfl(a0, len, 64);
    float al2 = __shfl(a1, (len > 0) ? len - 1 : 0, 64);
    al2 = (len > 0) ? al2 : 0.f;
    if (lane == 0) {
        const float s   = ab2 + al2;
        const float nll = -(__logf(s) - (float)esum * 0.69314718056f);
        atomicAdd(out, nll * inv_b);
    }
}

extern "C" void kernel_launch(void* const* d_in, const int* in_sizes, int n_in,
                              void* d_out, int out_size, void* d_ws, size_t ws_size,
                              hipStream_t stream) {
    const int* labels   = (const int*)d_in[0];
    const float* logits = (const float*)d_in[1];
    float* out          = (float*)d_out;
    __half* em          = (__half*)d_ws;        // B*48*T*2 = 36 MB

    const int L = 45, V = 60;
    const int B = in_sizes[0] / L;
    const int T = in_sizes[1] / (B * V);

    hipMemsetAsync(out, 0, (size_t)out_size * sizeof(float), stream);
    ctc_emit<<<B * (T / TTILE), 256, 0, stream>>>(labels, logits, em, T, V, L);
    ctc_alpha<<<B, 64, 0, stream>>>(labels, em, out, T, L, 1.0f / (float)B);
}

// Round 2
// 170.867 us; speedup vs baseline: 1.2488x; 1.0661x over previous
//
#include <hip/hip_runtime.h>
#include <hip/hip_fp16.h>

#define BLANKC 59

typedef _Float16 half8 __attribute__((ext_vector_type(8)));

// Wave-wide shift-right-by-1 via DPP: VALU-speed cross-lane. Lane 0 gets `fill`.
__device__ __forceinline__ float wave_shr1(float x, float fill) {
    int r = __builtin_amdgcn_update_dpp(__float_as_int(fill), __float_as_int(x),
                                        0x138 /* WAVE_SHR:1 */, 0xF, 0xF, false);
    return __int_as_float(r);
}

template <int CTRL>
__device__ __forceinline__ float dpp_fmax(float x) {
    int r = __builtin_amdgcn_update_dpp(__float_as_int(x), __float_as_int(x),
                                        CTRL, 0xF, 0xF, false);
    return fmaxf(x, __int_as_float(r));
}

// Full-wave max, broadcast to all lanes (6 DPP fmax + readlane).
__device__ __forceinline__ float wave_max_bcast(float x) {
    x = dpp_fmax<0x111>(x);   // row_shr:1
    x = dpp_fmax<0x112>(x);   // row_shr:2
    x = dpp_fmax<0x114>(x);   // row_shr:4
    x = dpp_fmax<0x118>(x);   // row_shr:8
    x = dpp_fmax<0x142>(x);   // row_bcast:15
    x = dpp_fmax<0x143>(x);   // row_bcast:31
    return __int_as_float(__builtin_amdgcn_readlane(__float_as_int(x), 63));
}

// ---------------- Fused CTC: softmax+gather -> LDS -> linear-domain scan ----
// One block per batch element. Phase A: 4 waves stage logits tiles, compute
// softmax probabilities for the 46 needed vocab slots (45 labels + blank),
// writing halves DIRECTLY into the scan's LDS rows (no global workspace).
// Phase B: wave 0 runs the alpha recurrence in the linear domain with
// periodic power-of-2 renormalization; waves 1-3 retire.
#define TTILE 64
#define RS 392   // LDS row stride in halves: 784 B = 49 dwords (16B-aligned rows)

__global__ __launch_bounds__(256)
void ctc_fused(const int* __restrict__ labels, const float* __restrict__ logits,
               float* __restrict__ out, int T, int V, int L, float inv_b) {
    const int b   = blockIdx.x;
    const int tid = threadIdx.x;

    __shared__ float  ftile[TTILE][61];   // 15.6 KB, stride 61: conflict-free
    __shared__ __half S[47 * RS];         // 36.8 KB: rows 0..44 labels, 45 blank, 46 zeros
    __shared__ int    labs[64];

    if (tid < 64) labs[tid] = (tid < L) ? labels[(long)b * L + tid] : BLANKC;
    for (int i = tid; i < T; i += 256) S[46 * RS + i] = __float2half(0.f);

    // ---- Phase A: per 64-t tile, stage -> LSE -> gather probs into S ----
    const float* src = logits + (long)b * T * V;
    const int ntile = T / TTILE;                         // 6
    for (int tile = 0; tile < ntile; ++tile) {
        const float* s0 = src + (long)tile * TTILE * V;  // 3840 contiguous floats
        #pragma unroll
        for (int it = 0; it < 15; ++it) {
            const int idx = it * 256 + tid;
            const int r = idx / 60, c = idx - r * 60;
            ftile[r][c] = s0[idx];
        }
        __syncthreads();
        {   // 4 lanes per t
            const int t = tid >> 2;
            const int q = tid & 3;
            float s = 0.f;
            #pragma unroll
            for (int k = 0; k < 15; ++k) s += __expf(ftile[t][q * 15 + k]);
            s += __shfl_xor(s, 1, 64);
            s += __shfl_xor(s, 2, 64);
            const float lse = __logf(s);
            const int tg = tile * TTILE + t;
            #pragma unroll
            for (int j = 0; j < 12; ++j) {
                const int l = q * 12 + j;
                if (l < 46) {
                    const int v = (l < 45) ? labs[l] : BLANKC;
                    S[l * RS + tg] = __float2half(__expf(ftile[t][v] - lse));
                }
            }
        }
        __syncthreads();
    }

    // ---- Phase B: wave 0 only ----
    if (tid >= 64) return;
    const int lane = tid;

    const int labL = (lane < L) ? labs[lane] : BLANKC;
    const int labP = (lane >= 1 && lane < L) ? labs[lane - 1] : BLANKC;
    const float skipf = ((lane >= 1) && (lane < L) && (labL != BLANKC) && (labL != labP))
                        ? 1.0f : 0.0f;

    unsigned long long mk = __ballot((lane < L) && (labL != BLANKC));
    const int len = __popcll(mk);

    // Lane 45's s1 (state 91) and lanes >=46 are phantoms: feed them zeros so
    // they stay exactly 0 and never pollute the wave max.
    const __half* zrow = &S[46 * RS];
    const __half* rowL = (lane < 45) ? &S[lane * RS] : zrow;
    const __half* rowB = (lane < 46) ? &S[45 * RS] : zrow;

    half8 curL = *(const half8*)(rowL);
    half8 curB = *(const half8*)(rowB);

    // init at t=0, pre-scaled by 2^80 (anchor): only s=0,1 alive
    float a0 = (lane == 0) ? (float)curB[0] * 0x1p80f : 0.f;
    float a1 = (lane == 0) ? (float)curL[0] * 0x1p80f : 0.f;
    int esum = 80;                                       // stored = true * 2^esum

    auto step = [&](float eL, float eB) {
        const float p   = wave_shr1(a1, 0.0f);           // alpha_old[2l-1]
        const float t1  = a0 + a1;
        const float na0 = (a0 + p) * eB;
        const float na1 = fmaf(skipf, p, t1) * eL;
        a0 = na0; a1 = na1;
    };

    auto renorm = [&]() {
        const float m = wave_max_bcast(fmaxf(a0, a1));   // wave-uniform, > 0
        const int e = (__float_as_int(m) >> 23) & 0xff;
        int sexp = 207 - e;                              // scale max to ~2^80
        if (sexp > 127) sexp = 127;
        const float sc = __int_as_float((sexp + 127) << 23);   // 2^sexp
        a0 *= sc; a1 *= sc;
        esum += sexp;
    };

    const int NSEG = T / 8;                              // 48

    // chunk 0: t = 1..7 (prefetch chunk 1 first)
    half8 nL = *(const half8*)(rowL + 8);
    half8 nB = *(const half8*)(rowB + 8);
    #pragma unroll
    for (int i = 1; i < 8; ++i) step((float)curL[i], (float)curB[i]);
    renorm();

    for (int c = 1; c < NSEG - 1; ++c) {
        const half8 cL = nL, cB = nB;
        nL = *(const half8*)(rowL + (c + 1) * 8);        // prefetch next chunk
        nB = *(const half8*)(rowB + (c + 1) * 8);
        #pragma unroll
        for (int i = 0; i < 8; ++i) step((float)cL[i], (float)cB[i]);
        renorm();
    }
    #pragma unroll
    for (int i = 0; i < 8; ++i) step((float)nL[i], (float)nB[i]);

    // epilogue: end = 2*len -> lane len's a0; end-1 -> lane (len-1)'s a1
    const float ab2 = __shfl(a0, len, 64);
    float al2 = __shfl(a1, (len > 0) ? len - 1 : 0, 64);
    al2 = (len > 0) ? al2 : 0.f;
    if (lane == 0) {
        const float s   = ab2 + al2;
        const float nll = -(__logf(s) - (float)esum * 0.69314718056f);
        atomicAdd(out, nll * inv_b);
    }
}

extern "C" void kernel_launch(void* const* d_in, const int* in_sizes, int n_in,
                              void* d_out, int out_size, void* d_ws, size_t ws_size,
                              hipStream_t stream) {
    const int* labels   = (const int*)d_in[0];
    const float* logits = (const float*)d_in[1];
    float* out          = (float*)d_out;
    (void)d_ws; (void)ws_size;

    const int L = 45, V = 60;
    const int B = in_sizes[0] / L;
    const int T = in_sizes[1] / (B * V);

    hipMemsetAsync(out, 0, (size_t)out_size * sizeof(float), stream);
    ctc_fused<<<B, 256, 0, stream>>>(labels, logits, out, T, V, L, 1.0f / (float)B);
}

// Round 3
// 153.331 us; speedup vs baseline: 1.3916x; 1.1144x over previous
//
#include <hip/hip_runtime.h>
#include <hip/hip_fp16.h>

#define BLANKC 59

typedef _Float16 half8 __attribute__((ext_vector_type(8)));

// Wave-wide shift-right-by-1 via DPP: VALU-speed cross-lane. Lane 0 gets `fill`.
__device__ __forceinline__ float wave_shr1(float x, float fill) {
    int r = __builtin_amdgcn_update_dpp(__float_as_int(fill), __float_as_int(x),
                                        0x138 /* WAVE_SHR:1 */, 0xF, 0xF, false);
    return __int_as_float(r);
}

template <int CTRL>
__device__ __forceinline__ float dpp_fmax(float x) {
    int r = __builtin_amdgcn_update_dpp(__float_as_int(x), __float_as_int(x),
                                        CTRL, 0xF, 0xF, false);
    return fmaxf(x, __int_as_float(r));
}

// Full-wave max, broadcast to all lanes (6 DPP fmax + readlane).
__device__ __forceinline__ float wave_max_bcast(float x) {
    x = dpp_fmax<0x111>(x);   // row_shr:1
    x = dpp_fmax<0x112>(x);   // row_shr:2
    x = dpp_fmax<0x114>(x);   // row_shr:4
    x = dpp_fmax<0x118>(x);   // row_shr:8
    x = dpp_fmax<0x142>(x);   // row_bcast:15
    x = dpp_fmax<0x143>(x);   // row_bcast:31
    return __int_as_float(__builtin_amdgcn_readlane(__float_as_int(x), 63));
}

// ---------------- Streamed fused CTC ----------------------------------------
// One block (4 waves) per batch element. Per 64-t tile: all waves stage the
// next tile's logits into registers (HBM latency in flight) while wave 0
// advances the linear-domain alpha scan over the current tile's emissions,
// held in a small double-buffered LDS tile. LDS = 29.4 KB -> 5 blocks/CU, so
// each CU runs up to 5 concurrent scan waves + 20 staging waves.
#define TTILE 64
#define SDS 72   // Sd row stride in halves (144 B rows, 16B-aligned)

__global__ __launch_bounds__(256)
void ctc_fused(const int* __restrict__ labels, const float* __restrict__ logits,
               float* __restrict__ out, int T, int V, int L, float inv_b) {
    const int b    = blockIdx.x;
    const int tid  = threadIdx.x;
    const int lane = tid & 63;
    const int wid  = tid >> 6;

    __shared__ float  ftile[TTILE][61];      // 15.6 KB, stride 61: conflict-free
    __shared__ __half Sd[2][47][SDS];        // 13.5 KB; row 46 = zeros (phantom)
    __shared__ int    labs[64];

    if (tid < 64) labs[tid] = (tid < L) ? labels[(long)b * L + tid] : BLANKC;
    if (tid < SDS) {
        Sd[0][46][tid] = __float2half(0.f);
        Sd[1][46][tid] = __float2half(0.f);
    }

    const float* src = logits + (long)b * T * V;
    const int ntile = T / TTILE;                         // 6

    float rg[15];                                        // staged logits tile
    auto load_tile = [&](int kt) {
        const float* s0 = src + (long)kt * TTILE * V;    // 3840 contiguous floats
        #pragma unroll
        for (int it = 0; it < 15; ++it) rg[it] = s0[it * 256 + tid];
    };
    auto ftile_write = [&]() {
        #pragma unroll
        for (int it = 0; it < 15; ++it) {
            const int idx = it * 256 + tid;
            const int r = idx / 60, c = idx - r * 60;
            ftile[r][c] = rg[it];
        }
    };
    auto lse_gather = [&](int nb) {                      // 4 lanes per t
        const int t = tid >> 2;                          // 0..63 (tile-local)
        const int q = tid & 3;
        float s = 0.f;
        #pragma unroll
        for (int k = 0; k < 15; ++k) s += __expf(ftile[t][q * 15 + k]);
        s += __shfl_xor(s, 1, 64);
        s += __shfl_xor(s, 2, 64);
        const float lse = __logf(s);
        #pragma unroll
        for (int j = 0; j < 12; ++j) {
            const int l = q * 12 + j;
            if (l < 46) {
                const int v = (l < 45) ? labs[l] : BLANKC;
                Sd[nb][l][t] = __float2half(__expf(ftile[t][v] - lse));
            }
        }
    };

    // ---- scan state (lives in wave 0's registers across the whole kernel) --
    float a0 = 0.f, a1 = 0.f;
    int esum = 0;
    float skipf = 0.f;
    int len = 0, riL = 46, riB = 46;

    auto step = [&](float eL, float eB) {
        const float p   = wave_shr1(a1, 0.0f);           // alpha_old[2l-1]
        const float t1  = a0 + a1;
        const float na0 = (a0 + p) * eB;
        const float na1 = fmaf(skipf, p, t1) * eL;
        a0 = na0; a1 = na1;
    };
    auto renorm = [&]() {
        const float m = wave_max_bcast(fmaxf(a0, a1));   // wave-uniform, > 0
        const int e = (__float_as_int(m) >> 23) & 0xff;
        int sexp = 207 - e;                              // scale max to ~2^80
        if (sexp > 127) sexp = 127;
        const float sc = __int_as_float((sexp + 127) << 23);   // 2^sexp
        a0 *= sc; a1 *= sc;
        esum += sexp;
    };
    auto scan_tile = [&](int cb, bool first) {           // 64 steps over Sd[cb]
        const __half* rl = &Sd[cb][riL][0];
        const __half* rb = &Sd[cb][riB][0];
        half8 cL = *(const half8*)rl;
        half8 cB = *(const half8*)rb;
        half8 nL = *(const half8*)(rl + 8);              // prefetch chunk 1
        half8 nB = *(const half8*)(rb + 8);
        if (first) {
            a0 = (lane == 0) ? (float)cB[0] * 0x1p80f : 0.f;
            a1 = (lane == 0) ? (float)cL[0] * 0x1p80f : 0.f;
            esum = 80;
            #pragma unroll
            for (int i = 1; i < 8; ++i) step((float)cL[i], (float)cB[i]);
        } else {
            #pragma unroll
            for (int i = 0; i < 8; ++i) step((float)cL[i], (float)cB[i]);
        }
        renorm();
        #pragma unroll
        for (int c = 1; c < 8; ++c) {
            cL = nL; cB = nB;
            if (c < 7) {                                 // prefetch next chunk
                nL = *(const half8*)(rl + (c + 1) * 8);
                nB = *(const half8*)(rb + (c + 1) * 8);
            }
            #pragma unroll
            for (int i = 0; i < 8; ++i) step((float)cL[i], (float)cB[i]);
            renorm();
        }
    };

    // ---- prologue: produce tile 0 ----
    load_tile(0);
    __syncthreads();                 // labs + zero rows visible
    ftile_write();
    __syncthreads();
    lse_gather(0);

    {   // lane roles (uniform across waves; labs visible since first barrier)
        const int labL = (lane < L) ? labs[lane] : BLANKC;
        const int labP = (lane >= 1 && lane < L) ? labs[lane - 1] : BLANKC;
        skipf = ((lane >= 1) && (lane < L) && (labL != BLANKC) && (labL != labP))
                ? 1.0f : 0.0f;
        const unsigned long long mk = __ballot((lane < L) && (labL != BLANKC));
        len = __popcll(mk);
        riL = (lane < 45) ? lane : 46;                   // lane>=45 s1: phantom
        riB = (lane < 46) ? 45 : 46;
    }
    __syncthreads();                 // Sd[0] ready

    // ---- pipeline: load(k+1) | scan(k) -> barrier -> produce(k+1) ----
    int cur = 0;
    for (int kt = 0; kt < ntile - 1; ++kt) {
        load_tile(kt + 1);                               // global loads in flight
        if (wid == 0) scan_tile(cur, kt == 0);           // consume Sd[cur]
        ftile_write();                                   // waves 1-3 start now
        __syncthreads();                                 // ftile complete
        lse_gather(cur ^ 1);                             // produce Sd[cur^1]
        __syncthreads();                                 // Sd[cur^1] ready
        cur ^= 1;
    }
    if (wid != 0) return;
    scan_tile(cur, ntile == 1);                          // final tile

    // ---- epilogue: end = 2*len -> lane len's a0; end-1 -> lane (len-1)'s a1
    const float ab2 = __shfl(a0, len, 64);
    float al2 = __shfl(a1, (len > 0) ? len - 1 : 0, 64);
    al2 = (len > 0) ? al2 : 0.f;
    if (lane == 0) {
        const float s   = ab2 + al2;
        const float nll = -(__logf(s) - (float)esum * 0.69314718056f);
        atomicAdd(out, nll * inv_b);
    }
}

extern "C" void kernel_launch(void* const* d_in, const int* in_sizes, int n_in,
                              void* d_out, int out_size, void* d_ws, size_t ws_size,
                              hipStream_t stream) {
    const int* labels   = (const int*)d_in[0];
    const float* logits = (const float*)d_in[1];
    float* out          = (float*)d_out;
    (void)d_ws; (void)ws_size;

    const int L = 45, V = 60;
    const int B = in_sizes[0] / L;
    const int T = in_sizes[1] / (B * V);

    hipMemsetAsync(out, 0, (size_t)out_size * sizeof(float), stream);
    ctc_fused<<<B, 256, 0, stream>>>(labels, logits, out, T, V, L, 1.0f / (float)B);
}